// Round 9
// baseline (56.065 us; speedup 1.0000x reference)
//
#include <hip/hip_runtime.h>
#include <hip/hip_bf16.h>

#define N_ROWS 4096
#define TWO_N  8192
#define D      256
#define DB     512                     // bytes per z row

// z is pre-scaled by sqrt(log2(e)/T) so sim' = sim * log2(e)/0.07 comes out of
// the MFMA ready for exp2. pos/T = sim' * ln2.
#define K_SQRT_SCALE 4.5398159980773926f   // sqrt(1.4426950408889634/0.07)
#define K_LN2        0.6931471805599453f

// simexp tiling: 256x256 tiles, symmetric pairing (each unordered pair once).
// Block: 4 waves x 64 rows. B staged 64 cols at a time through 32 KB LDS.
#define WAVES         4
#define ROWS_PER_WAVE 64               // 4 strips of 16
#define BLOCK_ROWS    256
#define COL_CHUNK     256
#define STAGE_COLS    64
#define NSTAGES       (COL_CHUNK / STAGE_COLS)   // 4
#define N_TILES       (TWO_N / BLOCK_ROWS)       // 32

typedef __attribute__((ext_vector_type(8))) short short8;
typedef __attribute__((ext_vector_type(4))) float f32x4;

static __device__ inline unsigned short f2bf(float x) {
    __hip_bfloat16 h = __float2bfloat16(x);
    return __builtin_bit_cast(unsigned short, h);
}

// One wave per row: L2-normalize, scale, write bf16 row. Also zero S.
__global__ __launch_bounds__(256) void normalize_kernel(
        const float* __restrict__ emb_i, const float* __restrict__ emb_j,
        unsigned short* __restrict__ z, float* __restrict__ S) {
    const int gtid = blockIdx.x * 256 + threadIdx.x;
    if (gtid < TWO_N) S[gtid] = 0.0f;

    const int row  = gtid >> 6;        // one wave per row
    const int lane = threadIdx.x & 63;
    if (row >= TWO_N) return;

    const float* src = (row < N_ROWS) ? emb_i + (size_t)row * D
                                      : emb_j + (size_t)(row - N_ROWS) * D;
    float4 v = reinterpret_cast<const float4*>(src)[lane];
    float ss = v.x * v.x + v.y * v.y + v.z * v.z + v.w * v.w;
    #pragma unroll
    for (int m = 1; m < 64; m <<= 1) ss += __shfl_xor(ss, m);
    const float rn = K_SQRT_SCALE / fmaxf(sqrtf(ss), 1e-12f);

    ushort4 o;
    o.x = f2bf(v.x * rn);
    o.y = f2bf(v.y * rn);
    o.z = f2bf(v.z * rn);
    o.w = f2bf(v.w * rn);
    reinterpret_cast<ushort4*>(z + (size_t)row * D)[lane] = o;
}

// Symmetric tiles: grid (32, 17); tile (rt, ct=(bx+by)&31). by==0 -> diagonal
// tile (self-excluded, row sums only). by>0 -> computed once, contributes row
// sums to S[rows] AND col sums to S[cols] (exp(sim) symmetric). Col sums are
// accumulated per-wave in LDS (no in-loop global atomics -- r8 lesson: 16-lane
// same-line atomics + vmcnt drain at each barrier doubled stage time), then
// flushed as one coalesced 256-atomic volley at block end.
// by==16 covers d=16 tiles; bx>=16 there is the duplicate half -> early exit.
__global__ __launch_bounds__(256, 2) void simexp_kernel(
        const unsigned short* __restrict__ z,
        float* __restrict__ S, float* __restrict__ posv) {
    __shared__ unsigned short lds[STAGE_COLS * D];   // 32 KB, bank-swizzled
    __shared__ float colsum[WAVES][COL_CHUNK];       // 4 KB, wave-private rows

    const int bx = blockIdx.x, by = blockIdx.y;
    if (by == 16 && bx >= 16) return;                // cyclic d=16 double-cover
    const int rt = bx;
    const int ct = (bx + by) & (N_TILES - 1);
    const bool sym = (by != 0);                      // add transposed col sums

    const int tid  = threadIdx.x;
    const int lane = tid & 63;
    const int wave = tid >> 6;
    const int lmod = lane & 15;
    const int lhi  = lane >> 4;

    const int R      = rt * BLOCK_ROWS + wave * ROWS_PER_WAVE;
    const int cchunk = ct * COL_CHUNK;

    // Zero this wave's colsum row (wave-private: no barrier needed).
    #pragma unroll
    for (int i = 0; i < 4; ++i) colsum[wave][lane + i * 64] = 0.0f;

    // ---- A fragments: 4 strips x 8 k-steps, short8 (16B) each ----
    short8 a[4][8];
    #pragma unroll
    for (int s = 0; s < 4; ++s) {
        const unsigned short* arow = z + (size_t)(R + s * 16 + lmod) * D + lhi * 8;
        #pragma unroll
        for (int ks = 0; ks < 8; ++ks)
            a[s][ks] = *reinterpret_cast<const short8*>(arow + ks * 32);
    }

    // ---- staging addresses (linear LDS dest, inverse-swizzled global src) ----
    const int colq = tid >> 5;                    // 0..7 == col&7 for all i
    const int offb = (tid & 31) << 4;
    const int soffbase = colq * 512 + (offb ^ (colq << 4));
    const int ldsbase  = tid * 16;

    float sums[4][4];
    #pragma unroll
    for (int s = 0; s < 4; ++s)
        #pragma unroll
        for (int r = 0; r < 4; ++r) sums[s][r] = 0.0f;

    const char* zbytes = (const char*)z;

    #pragma unroll 1                               // pin codegen: do NOT unroll stages
    for (int st = 0; st < NSTAGES; ++st) {
        const int c0 = cchunk + st * STAGE_COLS;
        const char* src = zbytes + (size_t)c0 * DB + soffbase;
        #pragma unroll
        for (int i = 0; i < 8; ++i) {
            __builtin_amdgcn_global_load_lds(
                (const __attribute__((address_space(1))) unsigned int*)(src + i * 4096),
                (__attribute__((address_space(3))) unsigned int*)
                    ((char*)lds + ldsbase + i * 4096),
                16, 0, 0);
        }
        __syncthreads();   // compiler drains vmcnt before the barrier

        #pragma unroll
        for (int cs = 0; cs < 4; ++cs) {
            const int colL = cs * 16 + lmod;
            const int bswz = (colL & 7) << 4;
            const char* brow = (const char*)lds + colL * 512;

            f32x4 acc0 = {0.f, 0.f, 0.f, 0.f};
            f32x4 acc1 = {0.f, 0.f, 0.f, 0.f};
            f32x4 acc2 = {0.f, 0.f, 0.f, 0.f};
            f32x4 acc3 = {0.f, 0.f, 0.f, 0.f};
            #pragma unroll
            for (int ks = 0; ks < 8; ++ks) {
                short8 bk = *reinterpret_cast<const short8*>(
                    brow + (((ks * 64 + lhi * 16) ^ bswz)));
                acc0 = __builtin_amdgcn_mfma_f32_16x16x32_bf16(a[0][ks], bk, acc0, 0, 0, 0);
                acc1 = __builtin_amdgcn_mfma_f32_16x16x32_bf16(a[1][ks], bk, acc1, 0, 0, 0);
                acc2 = __builtin_amdgcn_mfma_f32_16x16x32_bf16(a[2][ks], bk, acc2, 0, 0, 0);
                acc3 = __builtin_amdgcn_mfma_f32_16x16x32_bf16(a[3][ks], bk, acc3, 0, 0, 0);
            }

            const int csub = c0 + cs * 16;
            float cacc = 0.0f;                    // col-sum partial (sym tiles)
            f32x4 accs[4] = {acc0, acc1, acc2, acc3};
            #pragma unroll
            for (int s = 0; s < 4; ++s) {
                const int rowt = R + s * 16;
                if (csub == rowt) {                       // diagonal subtile (by==0 only)
                    #pragma unroll
                    for (int r = 0; r < 4; ++r) {
                        float e = __builtin_amdgcn_exp2f(accs[s][r]);
                        sums[s][r] += (lmod != lhi * 4 + r) ? e : 0.0f;
                    }
                } else if (csub == (rowt ^ N_ROWS)) {     // positive-pair subtile
                    #pragma unroll
                    for (int r = 0; r < 4; ++r) {
                        if (lmod == lhi * 4 + r) {
                            const int row = rowt + lhi * 4 + r;
                            const float v = accs[s][r];
                            posv[row] = v;
                            posv[row ^ N_ROWS] = v;       // symmetric partner
                        }
                        float e = __builtin_amdgcn_exp2f(accs[s][r]);
                        sums[s][r] += e;
                        cacc += e;
                    }
                } else {                                  // fast path
                    #pragma unroll
                    for (int r = 0; r < 4; ++r) {
                        float e = __builtin_amdgcn_exp2f(accs[s][r]);
                        sums[s][r] += e;
                        cacc += e;
                    }
                }
            }

            if (sym) {                            // transposed contribution -> LDS
                cacc += __shfl_xor(cacc, 16);
                cacc += __shfl_xor(cacc, 32);
                if (lhi == 0)
                    colsum[wave][st * STAGE_COLS + cs * 16 + lmod] += cacc;
            }
        }
        __syncthreads();
    }

    // Col sums: one coalesced fire-and-forget atomic volley per block.
    if (sym) {
        float v = colsum[0][tid] + colsum[1][tid] + colsum[2][tid] + colsum[3][tid];
        atomicAdd(&S[cchunk + tid], v);
    }

    // Row sums: reduce the 16 lmod-lanes sharing each row, one atomic per row.
    #pragma unroll
    for (int s = 0; s < 4; ++s)
        #pragma unroll
        for (int r = 0; r < 4; ++r) {
            float v = sums[s][r];
            v += __shfl_xor(v, 1);
            v += __shfl_xor(v, 2);
            v += __shfl_xor(v, 4);
            v += __shfl_xor(v, 8);
            if (lmod == 0) atomicAdd(&S[R + s * 16 + lhi * 4 + r], v);
        }
}

__global__ __launch_bounds__(1024) void finalize_kernel(
        const float* __restrict__ S, const float* __restrict__ posv,
        float* __restrict__ out) {
    const int tid = threadIdx.x;
    float local = 0.0f;
    #pragma unroll
    for (int i = tid; i < TWO_N; i += 1024)
        local += logf(S[i]) - posv[i] * K_LN2;   // posv is sim*log2e/T
    #pragma unroll
    for (int m = 1; m < 64; m <<= 1) local += __shfl_xor(local, m);
    __shared__ float red[16];
    if ((tid & 63) == 0) red[tid >> 6] = local;
    __syncthreads();
    if (tid == 0) {
        float t = 0.0f;
        #pragma unroll
        for (int w = 0; w < 16; ++w) t += red[w];
        out[0] = t / (float)TWO_N;
    }
}

extern "C" void kernel_launch(void* const* d_in, const int* in_sizes, int n_in,
                              void* d_out, int out_size, void* d_ws, size_t ws_size,
                              hipStream_t stream) {
    const float* emb_i = (const float*)d_in[0];
    const float* emb_j = (const float*)d_in[1];
    float* out = (float*)d_out;

    unsigned short* z = (unsigned short*)d_ws;                    // 4 MB
    float* S    = (float*)((char*)d_ws + (size_t)TWO_N * D * 2);  // 32 KB
    float* posv = S + TWO_N;                                      // 32 KB

    normalize_kernel<<<TWO_N / 4, 256, 0, stream>>>(emb_i, emb_j, z, S);
    simexp_kernel<<<dim3(N_TILES, 17), 256, 0, stream>>>(z, S, posv);
    finalize_kernel<<<1, 1024, 0, stream>>>(S, posv, out);
}

// Round 10
// 53.492 us; speedup vs baseline: 1.0481x; 1.0481x over previous
//
#include <hip/hip_runtime.h>
#include <hip/hip_bf16.h>

#define N_ROWS 4096
#define TWO_N  8192
#define D      256
#define DB     512                     // bytes per z row

// z is pre-scaled by sqrt(log2(e)/T) so sim' = sim * log2(e)/0.07 comes out of
// the MFMA ready for exp2. pos/T = sim' * ln2.
#define K_SQRT_SCALE 4.5398159980773926f   // sqrt(1.4426950408889634/0.07)
#define K_LN2        0.6931471805599453f

// simexp tiling: block = 8 waves x 32 rows = 256 rows x 512 cols, staged
// 64 cols at a time through 32 KB swizzled LDS. Full area (no symmetry).
// 32 rows/wave -> a[2][8]=64 VGPR -> live set ~110 -> 4 waves/SIMD, no spill.
#define WAVES         8
#define ROWS_PER_WAVE 32               // 2 strips of 16
#define BLOCK_ROWS    256
#define COL_CHUNK     512
#define STAGE_COLS    64
#define NSTAGES       (COL_CHUNK / STAGE_COLS)   // 8
#define ROW_TILES     (TWO_N / BLOCK_ROWS)       // 32
#define COL_TILES     (TWO_N / COL_CHUNK)        // 16

typedef __attribute__((ext_vector_type(8))) short short8;
typedef __attribute__((ext_vector_type(4))) float f32x4;

static __device__ inline unsigned short f2bf(float x) {
    __hip_bfloat16 h = __float2bfloat16(x);
    return __builtin_bit_cast(unsigned short, h);
}

// One wave per row: L2-normalize, scale, write bf16 row. Also zero S.
__global__ __launch_bounds__(256) void normalize_kernel(
        const float* __restrict__ emb_i, const float* __restrict__ emb_j,
        unsigned short* __restrict__ z, float* __restrict__ S) {
    const int gtid = blockIdx.x * 256 + threadIdx.x;
    if (gtid < TWO_N) S[gtid] = 0.0f;

    const int row  = gtid >> 6;        // one wave per row
    const int lane = threadIdx.x & 63;
    if (row >= TWO_N) return;

    const float* src = (row < N_ROWS) ? emb_i + (size_t)row * D
                                      : emb_j + (size_t)(row - N_ROWS) * D;
    float4 v = reinterpret_cast<const float4*>(src)[lane];
    float ss = v.x * v.x + v.y * v.y + v.z * v.z + v.w * v.w;
    #pragma unroll
    for (int m = 1; m < 64; m <<= 1) ss += __shfl_xor(ss, m);
    const float rn = K_SQRT_SCALE / fmaxf(sqrtf(ss), 1e-12f);

    ushort4 o;
    o.x = f2bf(v.x * rn);
    o.y = f2bf(v.y * rn);
    o.z = f2bf(v.z * rn);
    o.w = f2bf(v.w * rn);
    reinterpret_cast<ushort4*>(z + (size_t)row * D)[lane] = o;
}

// Block: 8 waves x 32 rows = 256 rows x 512 cols. B staged 64 cols at a time
// through bank-swizzled LDS; A fragments (2 strips) in registers.
// 512 blocks = 2/CU, 16 waves/CU = 4 waves/SIMD: waves cover each other's
// latency (r9 lesson: 2 waves/SIMD was wave-starved at identical MFMA rate).
__global__ __launch_bounds__(512, 4) void simexp_kernel(
        const unsigned short* __restrict__ z,
        float* __restrict__ S, float* __restrict__ posv) {
    __shared__ unsigned short lds[STAGE_COLS * D];   // 32 KB, bank-swizzled

    const int tid  = threadIdx.x;
    const int lane = tid & 63;
    const int wave = tid >> 6;
    const int lmod = lane & 15;
    const int lhi  = lane >> 4;

    const int R      = blockIdx.x * BLOCK_ROWS + wave * ROWS_PER_WAVE;
    const int cchunk = blockIdx.y * COL_CHUNK;

    // ---- A fragments: 2 strips x 8 k-steps, short8 (16B) each ----
    short8 a[2][8];
    #pragma unroll
    for (int s = 0; s < 2; ++s) {
        const unsigned short* arow = z + (size_t)(R + s * 16 + lmod) * D + lhi * 8;
        #pragma unroll
        for (int ks = 0; ks < 8; ++ks)
            a[s][ks] = *reinterpret_cast<const short8*>(arow + ks * 32);
    }

    // ---- staging addresses (linear LDS dest, inverse-swizzled global src) ----
    // 512 threads x 16B = 8 KB per volley; 4 volleys per 32 KB stage.
    // Linear LDS byte L = i*8192 + tid*16 -> col = i*16 + (tid>>5),
    // off = (tid&31)<<4. Want LDS[col*512 + (kb ^ sw(col))] = G[col*512 + kb],
    // sw(col) = (col&7)<<4, col&7 == (tid>>5)&7.
    const int colq = tid >> 5;                    // 0..15
    const int offb = (tid & 31) << 4;
    const int soffbase = colq * 512 + (offb ^ ((colq & 7) << 4));
    const int ldsbase  = tid * 16;

    float sums[2][4];
    #pragma unroll
    for (int s = 0; s < 2; ++s)
        #pragma unroll
        for (int r = 0; r < 4; ++r) sums[s][r] = 0.0f;

    const char* zbytes = (const char*)z;

    #pragma unroll 1                               // pin codegen, keep pressure low
    for (int st = 0; st < NSTAGES; ++st) {
        const int c0 = cchunk + st * STAGE_COLS;
        const char* src = zbytes + (size_t)c0 * DB + soffbase;
        #pragma unroll
        for (int i = 0; i < 4; ++i) {
            __builtin_amdgcn_global_load_lds(
                (const __attribute__((address_space(1))) unsigned int*)(src + i * 8192),
                (__attribute__((address_space(3))) unsigned int*)
                    ((char*)lds + ldsbase + i * 8192),
                16, 0, 0);
        }
        __syncthreads();   // compiler drains vmcnt before the barrier

        #pragma unroll
        for (int cs = 0; cs < 4; ++cs) {
            const int colL = cs * 16 + lmod;
            const int bswz = (colL & 7) << 4;
            const char* brow = (const char*)lds + colL * 512;

            f32x4 acc0 = {0.f, 0.f, 0.f, 0.f};
            f32x4 acc1 = {0.f, 0.f, 0.f, 0.f};
            #pragma unroll
            for (int ks = 0; ks < 8; ++ks) {
                short8 bk = *reinterpret_cast<const short8*>(
                    brow + (((ks * 64 + lhi * 16) ^ bswz)));
                acc0 = __builtin_amdgcn_mfma_f32_16x16x32_bf16(a[0][ks], bk, acc0, 0, 0, 0);
                acc1 = __builtin_amdgcn_mfma_f32_16x16x32_bf16(a[1][ks], bk, acc1, 0, 0, 0);
            }

            const int csub = c0 + cs * 16;
            f32x4 accs[2] = {acc0, acc1};
            #pragma unroll
            for (int s = 0; s < 2; ++s) {
                const int rowt = R + s * 16;
                if (csub == rowt) {                       // diagonal subtile
                    #pragma unroll
                    for (int r = 0; r < 4; ++r) {
                        float e = __builtin_amdgcn_exp2f(accs[s][r]);
                        sums[s][r] += (lmod != lhi * 4 + r) ? e : 0.0f;
                    }
                } else if (csub == (rowt ^ N_ROWS)) {     // positive-pair subtile
                    #pragma unroll
                    for (int r = 0; r < 4; ++r) {
                        if (lmod == lhi * 4 + r)
                            posv[rowt + lhi * 4 + r] = accs[s][r];
                        sums[s][r] += __builtin_amdgcn_exp2f(accs[s][r]);
                    }
                } else {                                  // fast path
                    #pragma unroll
                    for (int r = 0; r < 4; ++r)
                        sums[s][r] += __builtin_amdgcn_exp2f(accs[s][r]);
                }
            }
        }
        __syncthreads();
    }

    // Row sums: reduce the 16 lmod-lanes sharing each row, one atomic per row.
    #pragma unroll
    for (int s = 0; s < 2; ++s)
        #pragma unroll
        for (int r = 0; r < 4; ++r) {
            float v = sums[s][r];
            v += __shfl_xor(v, 1);
            v += __shfl_xor(v, 2);
            v += __shfl_xor(v, 4);
            v += __shfl_xor(v, 8);
            if (lmod == 0) atomicAdd(&S[R + s * 16 + lhi * 4 + r], v);
        }
}

__global__ __launch_bounds__(1024) void finalize_kernel(
        const float* __restrict__ S, const float* __restrict__ posv,
        float* __restrict__ out) {
    const int tid = threadIdx.x;
    float local = 0.0f;
    #pragma unroll
    for (int i = tid; i < TWO_N; i += 1024)
        local += logf(S[i]) - posv[i] * K_LN2;   // posv is sim*log2e/T
    #pragma unroll
    for (int m = 1; m < 64; m <<= 1) local += __shfl_xor(local, m);
    __shared__ float red[16];
    if ((tid & 63) == 0) red[tid >> 6] = local;
    __syncthreads();
    if (tid == 0) {
        float t = 0.0f;
        #pragma unroll
        for (int w = 0; w < 16; ++w) t += red[w];
        out[0] = t / (float)TWO_N;
    }
}

extern "C" void kernel_launch(void* const* d_in, const int* in_sizes, int n_in,
                              void* d_out, int out_size, void* d_ws, size_t ws_size,
                              hipStream_t stream) {
    const float* emb_i = (const float*)d_in[0];
    const float* emb_j = (const float*)d_in[1];
    float* out = (float*)d_out;

    unsigned short* z = (unsigned short*)d_ws;                    // 4 MB
    float* S    = (float*)((char*)d_ws + (size_t)TWO_N * D * 2);  // 32 KB
    float* posv = S + TWO_N;                                      // 32 KB

    normalize_kernel<<<TWO_N / 4, 256, 0, stream>>>(emb_i, emb_j, z, S);
    simexp_kernel<<<dim3(ROW_TILES, COL_TILES), 512, 0, stream>>>(z, S, posv);
    finalize_kernel<<<1, 1024, 0, stream>>>(S, posv, out);
}